// Round 2
// baseline (280.876 us; speedup 1.0000x reference)
//
#include <hip/hip_runtime.h>
#include <stdint.h>

#define E_N 8192
#define KVSPLIT 8
#define KVSTEPS ((E_N / KVSPLIT) / 64)   // 16

typedef unsigned short u16;
typedef unsigned int u32;
typedef __attribute__((ext_vector_type(4))) float f32x4;
typedef __attribute__((ext_vector_type(8))) short bf16x8;
typedef __attribute__((ext_vector_type(4))) unsigned int u32x4;
typedef __attribute__((ext_vector_type(2))) unsigned int u32x2;

union V16 { u32x4 q; bf16x8 h; u16 u[8]; };

static __device__ __forceinline__ u16 f2bf(float f) {
  union { float f; unsigned u; } c; c.f = f;
  unsigned r = c.u + 0x7FFFu + ((c.u >> 16) & 1u);
  return (u16)(r >> 16);
}

// direct global->LDS async copy, 16B per lane; LDS dest is wave-uniform base + lane*16
#define GLDS16(gp, lp) __builtin_amdgcn_global_load_lds( \
    (const __attribute__((address_space(1))) u32*)(gp), \
    (__attribute__((address_space(3))) u32*)(u32)(uintptr_t)(lp), 16, 0, 0)

// q pre-scale folds softmax 1/sqrt(128) and log2(e) so inner loop is exp2.
constexpr float QS = 1.4426950408889634f / 11.313708498984761f;

// ---------- kernel 0: W[256][128] f32 -> Wt bf16 [2][128][256]
__global__ void k_wt(const float* __restrict__ Wq, const float* __restrict__ Wk,
                     u16* __restrict__ wt) {
  int idx = blockIdx.x * 256 + threadIdx.x;          // 0..65535
  int mat = idx >> 15, rem = idx & 32767;
  float v = mat ? Wk[rem] : Wq[rem];
  int d = rem >> 7, c = rem & 127;
  wt[(mat * 128 + c) * 256 + d] = f2bf(v);
}

// ---------- kernel 1: projections q (scaled) and k, bf16 [8192][128]
__launch_bounds__(256)
__global__ void k_proj(const float* __restrict__ X, const u16* __restrict__ wt,
                       u16* __restrict__ qg, u16* __restrict__ kg) {
  __shared__ __align__(16) char Xs[64 * 512];        // bf16 [64][256], xor-swizzled
  const int tid = threadIdx.x;
  const int wid = tid >> 6, lane = tid & 63, g = lane >> 4, l15 = lane & 15;
  const int r0 = blockIdx.x * 64;
#pragma unroll
  for (int i = 0; i < 16; ++i) {
    int s = tid + 256 * i;                           // 0..4095 float4 tasks
    int row = s >> 6, c4 = (s & 63) << 2;
    f32x4 v = *(const f32x4*)(X + (size_t)(r0 + row) * 256 + c4);
    u32x2 pk;
    pk[0] = f2bf(v[0]) | ((unsigned)f2bf(v[1]) << 16);
    pk[1] = f2bf(v[2]) | ((unsigned)f2bf(v[3]) << 16);
    *(u32x2*)(Xs + (((row << 9) + (c4 << 1)) ^ ((row & 7) << 4))) = pk;
  }
  __syncthreads();
  bf16x8 xa[8];
  const int arow = wid * 16 + l15;
#pragma unroll
  for (int ks = 0; ks < 8; ++ks) {
    V16 t; t.q = *(const u32x4*)(Xs + (((arow << 9) + (ks << 6) + (g << 4)) ^ ((l15 & 7) << 4)));
    xa[ks] = t.h;
  }
  const f32x4 zero4 = {0.f, 0.f, 0.f, 0.f};
  f32x4 acc[16];
#pragma unroll
  for (int i = 0; i < 16; ++i) acc[i] = zero4;
#pragma unroll
  for (int ct = 0; ct < 16; ++ct) {
    int mat = ct >> 3, c = ((ct & 7) << 4) + l15;
#pragma unroll
    for (int ks = 0; ks < 8; ++ks) {
      V16 b; b.q = *(const u32x4*)(wt + ((mat * 128 + c) * 256 + (ks << 5) + (g << 3)));
      acc[ct] = __builtin_amdgcn_mfma_f32_16x16x32_bf16(xa[ks], b.h, acc[ct], 0, 0, 0);
    }
  }
#pragma unroll
  for (int ct = 0; ct < 16; ++ct) {
    int mat = ct >> 3, c = ((ct & 7) << 4) + l15;
#pragma unroll
    for (int r = 0; r < 4; ++r) {
      int row = r0 + wid * 16 + 4 * g + r;
      float v = acc[ct][r];
      if (mat == 0) qg[row * 128 + c] = f2bf(v * QS);
      else          kg[row * 128 + c] = f2bf(v);
    }
  }
}

// ---------- kernel 2: kt[128][8192] = k^T (bf16), LDS-tiled transpose
__global__ void k_kt(const u16* __restrict__ kg, u16* __restrict__ ktg) {
  __shared__ __align__(16) u16 Ts[64 * 66];          // pitch 66 (132 B) for bank spread
  const int tid = threadIdx.x;
  const int b = blockIdx.x;
  const int r0 = (b >> 1) * 64, c0 = (b & 1) * 64;
#pragma unroll
  for (int i = 0; i < 2; ++i) {
    int s = tid + 256 * i;                           // 0..511
    int row = s >> 3, seg = s & 7;
    u32x4 v = *(const u32x4*)(kg + (size_t)(r0 + row) * 128 + c0 + seg * 8);
    unsigned* dst = (unsigned*)((char*)Ts + row * 132 + seg * 16);
    dst[0] = v[0]; dst[1] = v[1]; dst[2] = v[2]; dst[3] = v[3];
  }
  __syncthreads();
#pragma unroll
  for (int i = 0; i < 2; ++i) {
    int s = tid + 256 * i;
    int oc = s >> 3, seg2 = s & 7;
    u16 t[8];
#pragma unroll
    for (int j = 0; j < 8; ++j) t[j] = Ts[(seg2 * 8 + j) * 66 + oc];
    u32x4 o;
    o[0] = t[0] | ((unsigned)t[1] << 16);
    o[1] = t[2] | ((unsigned)t[3] << 16);
    o[2] = t[4] | ((unsigned)t[5] << 16);
    o[3] = t[6] | ((unsigned)t[7] << 16);
    *(u32x4*)(ktg + (size_t)(c0 + oc) * E_N + r0 + seg2 * 8) = o;
  }
}

// ---------- kernel 3: fused masked-softmax attention (flash, no-max variant)
// grid 1024: split = bid&7 (XCD-aligned: round-robin dispatch puts each split
// on one XCD whose L2 then holds only that split's 1MB K/Kt slice),
// qb = bid>>3. Diagonal chunk stagger (st+qb)&15 spreads the 256B mask
// column-stripes across all offsets mod 32KB -> full HBM channel coverage.
__launch_bounds__(256, 4)
__global__ void k_flash(const u16* __restrict__ qg, const u16* __restrict__ kg,
                        const u16* __restrict__ ktg, const int* __restrict__ maskp,
                        float* __restrict__ Op, float* __restrict__ lp) {
  __shared__ __align__(16) char Ksh[64 * 256];       // bf16 [64][128], xor-swizzled (16KB)
  __shared__ __align__(16) char Kts[128 * 128];      // bf16 [128][64], xor-swizzled (16KB)
  __shared__ __align__(16) char Psh[4 * 2048];       // per-wave P tile bf16 [16][64], swizzled (8KB)
  const int tid = threadIdx.x;
  const int wid = tid >> 6, lane = tid & 63, g = lane >> 4, l15 = lane & 15;
  const int bid = blockIdx.x;
  const int split = bid & 7, qb = bid >> 3;
  const int qb0 = qb * 64;
  const int kvbase = split * (E_N / KVSPLIT);

  bf16x8 qf[4];
  {
    const u16* qrow = qg + (size_t)(qb0 + wid * 16 + l15) * 128;
#pragma unroll
    for (int ks = 0; ks < 4; ++ks) {
      V16 t; t.q = *(const u32x4*)(qrow + (ks << 5) + (g << 3));
      qf[ks] = t.h;
    }
  }
  const f32x4 zero4 = {0.f, 0.f, 0.f, 0.f};
  f32x4 Oacc[8];
#pragma unroll
  for (int i = 0; i < 8; ++i) Oacc[i] = zero4;
  float lacc[4] = {0.f, 0.f, 0.f, 0.f};
  char* Pw = Psh + wid * 2048;
  const int* mrow = maskp + (size_t)(qb0 + wid * 16 + 4 * g) * E_N + kvbase + l15;

  // staging lane geometry (linear LDS dest, inverse-swizzled global source)
  const int krow_st = lane >> 4, kseg_st = lane & 15;  // K: 4 rows/chunk, 16 segs
  const int trow_st = lane >> 3, tseg_st = lane & 7;   // Kt: 8 rows/chunk, 8 segs

  int mreg[16];
  {
    const int* mb = mrow + (qb & 15) * 64;
#pragma unroll
    for (int t = 0; t < 4; ++t)
#pragma unroll
      for (int r = 0; r < 4; ++r)
        mreg[t * 4 + r] = __builtin_nontemporal_load(mb + r * E_N + t * 16);
  }

  for (int st = 0; st < KVSTEPS; ++st) {
    const int sp = (st + qb) & 15;                   // staggered chunk
    const int kv0 = kvbase + sp * 64;
    __syncthreads();                                 // all waves done reading prev tiles
    // stage K [64][128] and Kt [128][64] tiles via global_load_lds (16B/lane)
#pragma unroll
    for (int i = 0; i < 4; ++i) {
      int ch = i * 4 + wid;                          // 0..15, wave-uniform
      int row = ch * 4 + krow_st;
      int seg = kseg_st ^ (row & 7);
      GLDS16(kg + (size_t)(kv0 + row) * 128 + seg * 8, Ksh + ch * 1024);
      int drow = ch * 8 + trow_st;
      int dseg = tseg_st ^ (drow & 7);
      GLDS16(ktg + (size_t)drow * E_N + kv0 + dseg * 8, Kts + ch * 1024);
    }
    __syncthreads();                                 // drains staging (+ mask prefetch)

    // S = q @ k^T (q pre-scaled; result is the log2-domain exponent)
    f32x4 S[4];
#pragma unroll
    for (int t = 0; t < 4; ++t) S[t] = zero4;
#pragma unroll
    for (int t = 0; t < 4; ++t) {
      int krow = t * 16 + l15;
#pragma unroll
      for (int ks = 0; ks < 4; ++ks) {
        V16 kf; kf.q = *(const u32x4*)(Ksh + (((krow << 8) + (ks << 6) + (g << 4)) ^ ((l15 & 7) << 4)));
        S[t] = __builtin_amdgcn_mfma_f32_16x16x32_bf16(qf[ks], kf.h, S[t], 0, 0, 0);
      }
    }

    // p = mask ? exp2(S) : 0 ; accumulate l ; store P as bf16 in swizzled LDS
#pragma unroll
    for (int t = 0; t < 4; ++t) {
#pragma unroll
      for (int r = 0; r < 4; ++r) {
        float pv = mreg[t * 4 + r] ? __builtin_amdgcn_exp2f(S[t][r]) : 0.f;
        lacc[r] += pv;
        int prow = 4 * g + r;
        *(u16*)(Pw + ((prow * 128 + (t * 16 + l15) * 2) ^ ((prow & 7) << 4))) = f2bf(pv);
      }
    }

    // prefetch next step's mask (mreg dead now; streams under PV + next staging)
    if (st + 1 < KVSTEPS) {
      const int* mb = mrow + ((st + 1 + qb) & 15) * 64;
#pragma unroll
      for (int t = 0; t < 4; ++t)
#pragma unroll
        for (int r = 0; r < 4; ++r)
          mreg[t * 4 + r] = __builtin_nontemporal_load(mb + r * E_N + t * 16);
    }

    // A-fragments of P straight from LDS (bf16, 16B aligned)
    bf16x8 pa[2];
#pragma unroll
    for (int ks2 = 0; ks2 < 2; ++ks2) {
      V16 t2; t2.q = *(const u32x4*)(Pw + ((l15 * 128 + ks2 * 64 + g * 16) ^ ((l15 & 7) << 4)));
      pa[ks2] = t2.h;
    }
    // O += P @ k  (B-frags from transposed Kt tile)
#pragma unroll
    for (int dt = 0; dt < 8; ++dt) {
      int krow = dt * 16 + l15;
#pragma unroll
      for (int ks2 = 0; ks2 < 2; ++ks2) {
        V16 kf; kf.q = *(const u32x4*)(Kts + (((krow << 7) + (ks2 << 6) + (g << 4)) ^ ((l15 & 7) << 4)));
        Oacc[dt] = __builtin_amdgcn_mfma_f32_16x16x32_bf16(pa[ks2], kf.h, Oacc[dt], 0, 0, 0);
      }
    }
  }

  // reduce row sums across the 16 lanes of each group
#pragma unroll
  for (int r = 0; r < 4; ++r) {
    float v = lacc[r];
    v += __shfl_xor(v, 1);
    v += __shfl_xor(v, 2);
    v += __shfl_xor(v, 4);
    v += __shfl_xor(v, 8);
    lacc[r] = v;
  }
  if (l15 == 0) {
#pragma unroll
    for (int r = 0; r < 4; ++r)
      lp[split * E_N + qb0 + wid * 16 + 4 * g + r] = lacc[r];
  }
  float* op = Op + ((size_t)split * E_N + qb0 + wid * 16) * 128;
#pragma unroll
  for (int dt = 0; dt < 8; ++dt)
#pragma unroll
    for (int r = 0; r < 4; ++r)
      op[(4 * g + r) * 128 + dt * 16 + l15] = Oacc[dt][r];
}

// ---------- kernel 4: combine KV-split partials, normalize (float4)
__global__ void k_comb(const float* __restrict__ Op, const float* __restrict__ lp,
                       float* __restrict__ out) {
  int idx4 = blockIdx.x * 256 + threadIdx.x;       // < 8192*128/4
  int base = idx4 << 2;
  int e = base >> 7;
  f32x4 o = {0.f, 0.f, 0.f, 0.f};
  float l = 0.f;
#pragma unroll
  for (int s = 0; s < KVSPLIT; ++s) {
    o += *(const f32x4*)(Op + (size_t)s * (E_N * 128) + base);
    l += lp[s * E_N + e];
  }
  float rl = 1.0f / l;
  o[0] *= rl; o[1] *= rl; o[2] *= rl; o[3] *= rl;
  *(f32x4*)(out + base) = o;
}

extern "C" void kernel_launch(void* const* d_in, const int* in_sizes, int n_in,
                              void* d_out, int out_size, void* d_ws, size_t ws_size,
                              hipStream_t stream) {
  const float* X  = (const float*)d_in[0];
  const float* Wq = (const float*)d_in[1];
  const float* Wk = (const float*)d_in[2];
  const int*   M  = (const int*)d_in[3];
  char* ws = (char*)d_ws;
  u16*   qg  = (u16*)(ws);                                      // 2 MB
  u16*   kg  = (u16*)(ws + (size_t)(2u << 20));                 // 2 MB
  u16*   ktg = (u16*)(ws + (size_t)(4u << 20));                 // 2 MB
  u16*   wt  = (u16*)(ws + (size_t)(6u << 20));                 // 128 KB
  float* lp  = (float*)(ws + (size_t)(6u << 20) + (1u << 17));  // 256 KB
  float* Op  = (float*)(ws + (size_t)(7u << 20));               // 33.5 MB
  float* out = (float*)d_out;

  k_wt  <<<256, 256, 0, stream>>>(Wq, Wk, wt);
  k_proj<<<128, 256, 0, stream>>>(X, wt, qg, kg);
  k_kt  <<<256, 256, 0, stream>>>(kg, ktg);
  k_flash<<<KVSPLIT * (E_N / 64), 256, 0, stream>>>(qg, kg, ktg, M, Op, lp);
  k_comb<<<(E_N * 128 / 4) / 256, 256, 0, stream>>>(Op, lp, out);
}

// Round 3
// 266.664 us; speedup vs baseline: 1.0533x; 1.0533x over previous
//
#include <hip/hip_runtime.h>
#include <stdint.h>

#define E_N 8192

typedef unsigned short u16;
typedef unsigned int u32;
typedef __attribute__((ext_vector_type(4))) float f32x4;
typedef __attribute__((ext_vector_type(8))) short bf16x8;
typedef __attribute__((ext_vector_type(4))) unsigned int u32x4;
typedef __attribute__((ext_vector_type(2))) unsigned int u32x2;

union V16 { u32x4 q; bf16x8 h; u16 u[8]; };

static __device__ __forceinline__ u16 f2bf(float f) {
  union { float f; unsigned u; } c; c.f = f;
  unsigned r = c.u + 0x7FFFu + ((c.u >> 16) & 1u);
  return (u16)(r >> 16);
}

// direct global->LDS async copy, 16B per lane; LDS dest is wave-uniform base + lane*16
#define GLDS16(gp, lp) __builtin_amdgcn_global_load_lds( \
    (const __attribute__((address_space(1))) u32*)(gp), \
    (__attribute__((address_space(3))) u32*)(u32)(uintptr_t)(lp), 16, 0, 0)

// q pre-scale folds softmax 1/sqrt(128) and log2(e) so inner loop is exp2.
constexpr float QS = 1.4426950408889634f / 11.313708498984761f;

// ---------- kernel 0: W[256][128] f32 -> Wt bf16 [2][128][256]
__global__ void k_wt(const float* __restrict__ Wq, const float* __restrict__ Wk,
                     u16* __restrict__ wt) {
  int idx = blockIdx.x * 256 + threadIdx.x;          // 0..65535
  int mat = idx >> 15, rem = idx & 32767;
  float v = mat ? Wk[rem] : Wq[rem];
  int d = rem >> 7, c = rem & 127;
  wt[(mat * 128 + c) * 256 + d] = f2bf(v);
}

// ---------- kernel 1: projections q (scaled) and k, bf16 [8192][128]
__launch_bounds__(256)
__global__ void k_proj(const float* __restrict__ X, const u16* __restrict__ wt,
                       u16* __restrict__ qg, u16* __restrict__ kg) {
  __shared__ __align__(16) char Xs[64 * 512];        // bf16 [64][256], xor-swizzled
  const int tid = threadIdx.x;
  const int wid = tid >> 6, lane = tid & 63, g = lane >> 4, l15 = lane & 15;
  const int r0 = blockIdx.x * 64;
#pragma unroll
  for (int i = 0; i < 16; ++i) {
    int s = tid + 256 * i;                           // 0..4095 float4 tasks
    int row = s >> 6, c4 = (s & 63) << 2;
    f32x4 v = *(const f32x4*)(X + (size_t)(r0 + row) * 256 + c4);
    u32x2 pk;
    pk[0] = f2bf(v[0]) | ((unsigned)f2bf(v[1]) << 16);
    pk[1] = f2bf(v[2]) | ((unsigned)f2bf(v[3]) << 16);
    *(u32x2*)(Xs + (((row << 9) + (c4 << 1)) ^ ((row & 7) << 4))) = pk;
  }
  __syncthreads();
  bf16x8 xa[8];
  const int arow = wid * 16 + l15;
#pragma unroll
  for (int ks = 0; ks < 8; ++ks) {
    V16 t; t.q = *(const u32x4*)(Xs + (((arow << 9) + (ks << 6) + (g << 4)) ^ ((l15 & 7) << 4)));
    xa[ks] = t.h;
  }
  const f32x4 zero4 = {0.f, 0.f, 0.f, 0.f};
  f32x4 acc[16];
#pragma unroll
  for (int i = 0; i < 16; ++i) acc[i] = zero4;
#pragma unroll
  for (int ct = 0; ct < 16; ++ct) {
    int mat = ct >> 3, c = ((ct & 7) << 4) + l15;
#pragma unroll
    for (int ks = 0; ks < 8; ++ks) {
      V16 b; b.q = *(const u32x4*)(wt + ((mat * 128 + c) * 256 + (ks << 5) + (g << 3)));
      acc[ct] = __builtin_amdgcn_mfma_f32_16x16x32_bf16(xa[ks], b.h, acc[ct], 0, 0, 0);
    }
  }
#pragma unroll
  for (int ct = 0; ct < 16; ++ct) {
    int mat = ct >> 3, c = ((ct & 7) << 4) + l15;
#pragma unroll
    for (int r = 0; r < 4; ++r) {
      int row = r0 + wid * 16 + 4 * g + r;
      float v = acc[ct][r];
      if (mat == 0) qg[row * 128 + c] = f2bf(v * QS);
      else          kg[row * 128 + c] = f2bf(v);
    }
  }
}

// ---------- kernel 2: kt[128][8192] = k^T (bf16), LDS-tiled transpose
__global__ void k_kt(const u16* __restrict__ kg, u16* __restrict__ ktg) {
  __shared__ __align__(16) u16 Ts[64 * 66];          // pitch 66 (132 B) for bank spread
  const int tid = threadIdx.x;
  const int b = blockIdx.x;
  const int r0 = (b >> 1) * 64, c0 = (b & 1) * 64;
#pragma unroll
  for (int i = 0; i < 2; ++i) {
    int s = tid + 256 * i;                           // 0..511
    int row = s >> 3, seg = s & 7;
    u32x4 v = *(const u32x4*)(kg + (size_t)(r0 + row) * 128 + c0 + seg * 8);
    unsigned* dst = (unsigned*)((char*)Ts + row * 132 + seg * 16);
    dst[0] = v[0]; dst[1] = v[1]; dst[2] = v[2]; dst[3] = v[3];
  }
  __syncthreads();
#pragma unroll
  for (int i = 0; i < 2; ++i) {
    int s = tid + 256 * i;
    int oc = s >> 3, seg2 = s & 7;
    u16 t[8];
#pragma unroll
    for (int j = 0; j < 8; ++j) t[j] = Ts[(seg2 * 8 + j) * 66 + oc];
    u32x4 o;
    o[0] = t[0] | ((unsigned)t[1] << 16);
    o[1] = t[2] | ((unsigned)t[3] << 16);
    o[2] = t[4] | ((unsigned)t[5] << 16);
    o[3] = t[6] | ((unsigned)t[7] << 16);
    *(u32x4*)(ktg + (size_t)(c0 + oc) * E_N + r0 + seg2 * 8) = o;
  }
}

// ---------- kernel 2b: pack mask int32 [8192][8192] -> bits u32 [8192][256]
// One wave per row. Lane l loads col c*64+l (256B coalesced); ballot -> 64-bit
// mask word in exactly the layout k_flash consumes. The ONLY big HBM stream.
__launch_bounds__(256)
__global__ void k_pack(const int* __restrict__ M, u32* __restrict__ bits) {
  const int row = blockIdx.x * 4 + (threadIdx.x >> 6);
  const int lane = threadIdx.x & 63;
  const int* rp = M + (size_t)row * E_N + lane;
  u32* op = bits + (size_t)row * 256;
#pragma unroll 4
  for (int cc = 0; cc < 64; ++cc) {
    int v0 = rp[(2 * cc) * 64];
    int v1 = rp[(2 * cc + 1) * 64];
    unsigned long long b0 = __ballot(v0 != 0);
    unsigned long long b1 = __ballot(v1 != 0);
    if (lane == 0) {
      u32x4 o = {(u32)b0, (u32)(b0 >> 32), (u32)b1, (u32)(b1 >> 32)};
      *(u32x4*)(op + cc * 4) = o;
    }
  }
}

// ---------- kernel 3: fused masked-softmax attention (flash, no-max variant)
// split = bid & (SPLIT-1) -> XCD-aligned; qb = bid / SPLIT. Diagonal chunk
// stagger (st+qb) spreads K/Kt L2 access. Mask comes from the 8 MB bit array
// (L2/L3-resident, each bit read exactly once).
template <int SPLIT>
__launch_bounds__(256, 4)
__global__ void k_flash(const u16* __restrict__ qg, const u16* __restrict__ kg,
                        const u16* __restrict__ ktg, const u32* __restrict__ bits,
                        float* __restrict__ Op, float* __restrict__ lp) {
  constexpr int CH = (E_N / SPLIT) / 64;             // kv chunks per split
  __shared__ __align__(16) char Ksh[64 * 256];       // bf16 [64][128], xor-swizzled (16KB)
  __shared__ __align__(16) char Kts[128 * 128];      // bf16 [128][64], xor-swizzled (16KB)
  __shared__ __align__(16) char Psh[4 * 2048];       // per-wave P bf16 [16][64], swizzled (8KB)
  const int tid = threadIdx.x;
  const int wid = tid >> 6, lane = tid & 63, g = lane >> 4, l15 = lane & 15;
  const int bid = blockIdx.x;
  const int split = bid & (SPLIT - 1), qb = bid / SPLIT;
  const int qb0 = qb * 64;
  const int kvbase = split * (E_N / SPLIT);
  const int c64base = split * CH;

  bf16x8 qf[4];
  {
    const u16* qrow = qg + (size_t)(qb0 + wid * 16 + l15) * 128;
#pragma unroll
    for (int ks = 0; ks < 4; ++ks) {
      V16 t; t.q = *(const u32x4*)(qrow + (ks << 5) + (g << 3));
      qf[ks] = t.h;
    }
  }
  const f32x4 zero4 = {0.f, 0.f, 0.f, 0.f};
  f32x4 Oacc[8];
#pragma unroll
  for (int i = 0; i < 8; ++i) Oacc[i] = zero4;
  float lacc[4] = {0.f, 0.f, 0.f, 0.f};
  char* Pw = Psh + wid * 2048;

  // staging lane geometry (linear LDS dest, inverse-swizzled global source)
  const int krow_st = lane >> 4, kseg_st = lane & 15;  // K: 4 rows/chunk, 16 segs
  const int trow_st = lane >> 3, tseg_st = lane & 7;   // Kt: 8 rows/chunk, 8 segs

  // mask bit words: 4 rows per lane-group (g), one u64 (u32x2) per row per step
  const u32* brow = bits + (size_t)(qb0 + wid * 16 + 4 * g) * 256;
  u32x2 wreg[4];
  {
    int sp0 = qb & (CH - 1);
#pragma unroll
    for (int r = 0; r < 4; ++r)
      wreg[r] = *(const u32x2*)(brow + r * 256 + 2 * (c64base + sp0));
  }

  for (int st = 0; st < CH; ++st) {
    const int sp = (st + qb) & (CH - 1);             // staggered chunk
    const int kv0 = kvbase + sp * 64;
    __syncthreads();                                 // all waves done reading prev tiles
    // stage K [64][128] and Kt [128][64] tiles via global_load_lds (16B/lane)
#pragma unroll
    for (int i = 0; i < 4; ++i) {
      int ch = i * 4 + wid;                          // 0..15, wave-uniform
      int row = ch * 4 + krow_st;
      int seg = kseg_st ^ (row & 7);
      GLDS16(kg + (size_t)(kv0 + row) * 128 + seg * 8, Ksh + ch * 1024);
      int drow = ch * 8 + trow_st;
      int dseg = tseg_st ^ (drow & 7);
      GLDS16(ktg + (size_t)drow * E_N + kv0 + dseg * 8, Kts + ch * 1024);
    }
    __syncthreads();                                 // drains staging

    // S = q @ k^T (q pre-scaled; result is the log2-domain exponent)
    f32x4 S[4];
#pragma unroll
    for (int t = 0; t < 4; ++t) S[t] = zero4;
#pragma unroll
    for (int t = 0; t < 4; ++t) {
      int krow = t * 16 + l15;
#pragma unroll
      for (int ks = 0; ks < 4; ++ks) {
        V16 kf; kf.q = *(const u32x4*)(Ksh + (((krow << 8) + (ks << 6) + (g << 4)) ^ ((l15 & 7) << 4)));
        S[t] = __builtin_amdgcn_mfma_f32_16x16x32_bf16(qf[ks], kf.h, S[t], 0, 0, 0);
      }
    }

    // p = maskbit ? exp2(S) : 0 ; accumulate l ; store P as bf16 in swizzled LDS
#pragma unroll
    for (int t = 0; t < 4; ++t) {
#pragma unroll
      for (int r = 0; r < 4; ++r) {
        u32 wsel = (t & 2) ? wreg[r][1] : wreg[r][0];
        float pv = ((wsel >> ((t & 1) * 16 + l15)) & 1u) ? __builtin_amdgcn_exp2f(S[t][r]) : 0.f;
        lacc[r] += pv;
        int prow = 4 * g + r;
        *(u16*)(Pw + ((prow * 128 + (t * 16 + l15) * 2) ^ ((prow & 7) << 4))) = f2bf(pv);
      }
    }

    // prefetch next step's mask words (wreg dead now)
    if (st + 1 < CH) {
      int spn = (st + 1 + qb) & (CH - 1);
#pragma unroll
      for (int r = 0; r < 4; ++r)
        wreg[r] = *(const u32x2*)(brow + r * 256 + 2 * (c64base + spn));
    }

    // A-fragments of P straight from LDS (bf16, 16B aligned)
    bf16x8 pa[2];
#pragma unroll
    for (int ks2 = 0; ks2 < 2; ++ks2) {
      V16 t2; t2.q = *(const u32x4*)(Pw + ((l15 * 128 + ks2 * 64 + g * 16) ^ ((l15 & 7) << 4)));
      pa[ks2] = t2.h;
    }
    // O += P @ k  (B-frags from transposed Kt tile)
#pragma unroll
    for (int dt = 0; dt < 8; ++dt) {
      int krow = dt * 16 + l15;
#pragma unroll
      for (int ks2 = 0; ks2 < 2; ++ks2) {
        V16 kf; kf.q = *(const u32x4*)(Kts + (((krow << 7) + (ks2 << 6) + (g << 4)) ^ ((l15 & 7) << 4)));
        Oacc[dt] = __builtin_amdgcn_mfma_f32_16x16x32_bf16(pa[ks2], kf.h, Oacc[dt], 0, 0, 0);
      }
    }
  }

  // reduce row sums across the 16 lanes of each group
#pragma unroll
  for (int r = 0; r < 4; ++r) {
    float v = lacc[r];
    v += __shfl_xor(v, 1);
    v += __shfl_xor(v, 2);
    v += __shfl_xor(v, 4);
    v += __shfl_xor(v, 8);
    lacc[r] = v;
  }
  if (l15 == 0) {
#pragma unroll
    for (int r = 0; r < 4; ++r)
      lp[split * E_N + qb0 + wid * 16 + 4 * g + r] = lacc[r];
  }
  float* op = Op + ((size_t)split * E_N + qb0 + wid * 16) * 128;
#pragma unroll
  for (int dt = 0; dt < 8; ++dt)
#pragma unroll
    for (int r = 0; r < 4; ++r)
      op[(4 * g + r) * 128 + dt * 16 + l15] = Oacc[dt][r];
}

// ---------- kernel 4: combine KV-split partials, normalize (float4)
template <int SPLIT>
__global__ void k_comb(const float* __restrict__ Op, const float* __restrict__ lp,
                       float* __restrict__ out) {
  int idx4 = blockIdx.x * 256 + threadIdx.x;       // < 8192*128/4
  int base = idx4 << 2;
  int e = base >> 7;
  f32x4 o = {0.f, 0.f, 0.f, 0.f};
  float l = 0.f;
#pragma unroll
  for (int s = 0; s < SPLIT; ++s) {
    o += *(const f32x4*)(Op + (size_t)s * (E_N * 128) + base);
    l += lp[s * E_N + e];
  }
  float rl = 1.0f / l;
  o[0] *= rl; o[1] *= rl; o[2] *= rl; o[3] *= rl;
  *(f32x4*)(out + base) = o;
}

extern "C" void kernel_launch(void* const* d_in, const int* in_sizes, int n_in,
                              void* d_out, int out_size, void* d_ws, size_t ws_size,
                              hipStream_t stream) {
  const float* X  = (const float*)d_in[0];
  const float* Wq = (const float*)d_in[1];
  const float* Wk = (const float*)d_in[2];
  const int*   M  = (const int*)d_in[3];
  char* ws = (char*)d_ws;
  u16*   qg   = (u16*)(ws);                                      // 2 MB
  u16*   kg   = (u16*)(ws + (size_t)(2u << 20));                 // 2 MB
  u16*   ktg  = (u16*)(ws + (size_t)(4u << 20));                 // 2 MB
  u16*   wt   = (u16*)(ws + (size_t)(6u << 20));                 // 128 KB
  float* lp   = (float*)(ws + (size_t)(6u << 20) + (128u << 10)); // 256 KB
  u32*   bits = (u32*)(ws + (size_t)(6u << 20) + (512u << 10));   // 8 MB @ 6.5 MB
  float* Op   = (float*)(ws + (size_t)(6u << 20) + (512u << 10) + (8u << 20)); // @14.5 MB
  float* out = (float*)d_out;

  k_wt  <<<256, 256, 0, stream>>>(Wq, Wk, wt);
  k_proj<<<128, 256, 0, stream>>>(X, wt, qg, kg);
  k_kt  <<<256, 256, 0, stream>>>(kg, ktg);
  k_pack<<<E_N / 4, 256, 0, stream>>>(M, bits);
  if (ws_size >= ((size_t)49 << 20)) {
    k_flash<8><<<8 * (E_N / 64), 256, 0, stream>>>(qg, kg, ktg, bits, Op, lp);
    k_comb<8><<<(E_N * 128 / 4) / 256, 256, 0, stream>>>(Op, lp, out);
  } else {
    k_flash<4><<<4 * (E_N / 64), 256, 0, stream>>>(qg, kg, ktg, bits, Op, lp);
    k_comb<4><<<(E_N * 128 / 4) / 256, 256, 0, stream>>>(Op, lp, out);
  }
}